// Round 1
// baseline (724.224 us; speedup 1.0000x reference)
//
#include <hip/hip_runtime.h>
#include <math.h>

constexpr int D = 128;

// ---------------- Kernel 1: per-node edge-score components ----------------
// s_d[v] = dot(nf[v], W_edge[0:128]), s_s[v] = dot(nf[v], W_edge[128:256])
__global__ __launch_bounds__(256) void k_node_scores(
    const float* __restrict__ nf, const float* __restrict__ W_edge,
    float* __restrict__ s_d, float* __restrict__ s_s, int N)
{
    int wave = threadIdx.x >> 6;
    int lane = threadIdx.x & 63;
    int v = blockIdx.x * 4 + wave;
    if (v >= N) return;
    const float* row = nf + (size_t)v * D;
    float a0 = row[lane], a1 = row[lane + 64];
    float pd = a0 * W_edge[lane] + a1 * W_edge[lane + 64];
    float ps = a0 * W_edge[128 + lane] + a1 * W_edge[192 + lane];
#pragma unroll
    for (int off = 32; off; off >>= 1) {
        pd += __shfl_down(pd, off);
        ps += __shfl_down(ps, off);
    }
    if (lane == 0) { s_d[v] = pd; s_s[v] = ps; }
}

// ---------------- Kernel 2: hv = nf @ W_proj + b_proj (batched GEMV) ------
__global__ __launch_bounds__(128) void k_hv(
    const float* __restrict__ nf, const float* __restrict__ W_proj,
    const float* __restrict__ b_proj, float* __restrict__ hv, int N)
{
    __shared__ float tile[32 * 128];
    int base = blockIdx.x * 32;
    int t = threadIdx.x;
    for (int idx = t; idx < 32 * 128; idx += 128) {
        int n = idx >> 7;
        tile[idx] = (base + n < N) ? nf[(size_t)base * 128 + idx] : 0.f;
    }
    __syncthreads();
    float acc[32];
#pragma unroll
    for (int n = 0; n < 32; ++n) acc[n] = 0.f;
    for (int k = 0; k < 128; ++k) {
        float w = W_proj[k * 128 + t];
#pragma unroll
        for (int n = 0; n < 32; ++n)
            acc[n] = fmaf(tile[n * 128 + k], w, acc[n]);
    }
    float b = b_proj[t];
    for (int n = 0; n < 32; ++n)
        if (base + n < N) hv[(size_t)(base + n) * 128 + t] = acc[n] + b;
}

// ---------------- Kernel 3: per-edge exp(leaky) + denom + counts ----------
__global__ void k_edge(
    const int* __restrict__ src, const int* __restrict__ dst,
    const float* __restrict__ s_d, const float* __restrict__ s_s,
    const float* __restrict__ b_edge, float* __restrict__ ex,
    float* __restrict__ denom, int* __restrict__ count, int E)
{
    int e = blockIdx.x * blockDim.x + threadIdx.x;
    if (e >= E) return;
    int s = src[e], t = dst[e];
    float l = s_d[t] + s_s[s] + b_edge[0];
    l = l > 0.f ? l : 0.01f * l;
    float ev = expf(l);
    ex[e] = ev;
    atomicAdd(&denom[t], ev);
    atomicAdd(&count[t], 1);
}

// ---------------- Scan (3-phase) for CSR row offsets ----------------------
__global__ __launch_bounds__(256) void k_scan_local(
    const int* __restrict__ count, int* __restrict__ lex,
    int* __restrict__ bsum, int N)
{
    __shared__ int sdata[256];
    int tid = threadIdx.x;
    int i = blockIdx.x * 256 + tid;
    int v = (i < N) ? count[i] : 0;
    int incl = v;
    sdata[tid] = incl; __syncthreads();
#pragma unroll
    for (int off = 1; off < 256; off <<= 1) {
        int add = (tid >= off) ? sdata[tid - off] : 0;
        __syncthreads();
        incl += add;
        sdata[tid] = incl;
        __syncthreads();
    }
    if (i < N) lex[i] = incl - v;
    if (tid == 255) bsum[blockIdx.x] = incl;
}

__global__ __launch_bounds__(256) void k_scan_blocks(int* __restrict__ bsum, int nb)
{
    __shared__ int sdata[256];
    int tid = threadIdx.x;
    int v = (tid < nb) ? bsum[tid] : 0;
    int incl = v;
    sdata[tid] = incl; __syncthreads();
#pragma unroll
    for (int off = 1; off < 256; off <<= 1) {
        int add = (tid >= off) ? sdata[tid - off] : 0;
        __syncthreads();
        incl += add;
        sdata[tid] = incl;
        __syncthreads();
    }
    if (tid < nb) bsum[tid] = incl - v;   // exclusive
}

__global__ __launch_bounds__(256) void k_scan_apply(
    const int* __restrict__ lex, const int* __restrict__ bsum,
    int* __restrict__ row_start, int* __restrict__ cursor, int N)
{
    int i = blockIdx.x * 256 + threadIdx.x;
    if (i < N) {
        int o = lex[i] + bsum[blockIdx.x];
        row_start[i] = o;
        cursor[i] = o;
    }
}

// ---------------- Fill CSR with pre-divided weights -----------------------
__global__ void k_fill(
    const int* __restrict__ src, const int* __restrict__ dst,
    const float* __restrict__ ex, const float* __restrict__ denom,
    int* __restrict__ cursor, int* __restrict__ edge_u,
    float* __restrict__ edge_w, int E)
{
    int e = blockIdx.x * blockDim.x + threadIdx.x;
    if (e >= E) return;
    int t = dst[e];
    int pos = atomicAdd(&cursor[t], 1);
    edge_u[pos] = src[e];
    edge_w[pos] = ex[e] / denom[t] + 1.0f;
}

// ---------------- Aggregate: ctx[v] = elu(sum hv[u]*w) --------------------
__global__ __launch_bounds__(128) void k_agg(
    const float* __restrict__ hv, const int* __restrict__ row_start,
    const int* __restrict__ count, const int* __restrict__ edge_u,
    const float* __restrict__ edge_w, float* __restrict__ ctx, int N)
{
    int v = blockIdx.x;
    if (v >= N) return;
    int d = threadIdx.x;
    int beg = row_start[v];
    int cnt = count[v];
    float c = 0.f;
    int i = 0;
    for (; i + 2 <= cnt; i += 2) {
        int u0 = edge_u[beg + i], u1 = edge_u[beg + i + 1];
        float w0 = edge_w[beg + i], w1 = edge_w[beg + i + 1];
        float h0 = hv[(size_t)u0 * 128 + d];
        float h1 = hv[(size_t)u1 * 128 + d];
        c = fmaf(h0, w0, c);
        c = fmaf(h1, w1, c);
    }
    if (i < cnt) {
        int u = edge_u[beg + i];
        c = fmaf(hv[(size_t)u * 128 + d], edge_w[beg + i], c);
    }
    float cx = c > 0.f ? c : expm1f(c);
    ctx[(size_t)v * 128 + d] = cx;
}

// ---------------- Transpose GRU weights to [128][384] ---------------------
__global__ void k_wt(
    const float* __restrict__ W_ih, const float* __restrict__ W_hh,
    float* __restrict__ W_ihT, float* __restrict__ W_hhT)
{
    int idx = blockIdx.x * 256 + threadIdx.x;
    if (idx >= 128 * 384) return;
    int k = idx / 384, j = idx - k * 384;
    W_ihT[idx] = W_ih[j * 128 + k];
    W_hhT[idx] = W_hh[j * 128 + k];
}

// ---------------- GRU + relu (32-node batch) ------------------------------
__global__ __launch_bounds__(384) void k_gru(
    const float* __restrict__ ctx, const float* __restrict__ nf,
    const float* __restrict__ W_ihT, const float* __restrict__ W_hhT,
    const float* __restrict__ b_ih, const float* __restrict__ b_hh,
    float* __restrict__ out, int N)
{
    __shared__ float smem[32 * 384 + 32 * 128];   // 64 KB
    float* ctx_s = smem;           // [32][128] during phase 1
    float* nfs_s = smem + 4096;    // [32][128] during phase 1
    int base = blockIdx.x * 32;
    int t = threadIdx.x;
    for (int idx = t; idx < 4096; idx += 384) {
        int n = idx >> 7;
        float cv = 0.f, hvv = 0.f;
        if (base + n < N) {
            cv = ctx[(size_t)base * 128 + idx];
            hvv = nf[(size_t)base * 128 + idx];
        }
        ctx_s[idx] = cv;
        nfs_s[idx] = hvv;
    }
    __syncthreads();
    float gi[32], gh[32];
#pragma unroll
    for (int n = 0; n < 32; ++n) { gi[n] = 0.f; gh[n] = 0.f; }
    for (int k = 0; k < 128; ++k) {
        float wa = W_ihT[k * 384 + t];
        float wb = W_hhT[k * 384 + t];
#pragma unroll
        for (int n = 0; n < 32; ++n) {
            gi[n] = fmaf(ctx_s[n * 128 + k], wa, gi[n]);
            gh[n] = fmaf(nfs_s[n * 128 + k], wb, gh[n]);
        }
    }
    float bi = b_ih[t], bh = b_hh[t];
    __syncthreads();                 // done with tiles; reuse smem
    float* A  = smem;                // [32][384] gate preacts
    float* HN = smem + 32 * 384;     // [32][128] h_n
#pragma unroll
    for (int n = 0; n < 32; ++n) {
        float a = gi[n] + bi;
        float b = gh[n] + bh;
        if (t >= 256) {
            A[n * 384 + t] = a;               // i_n
            HN[n * 128 + (t - 256)] = b;      // h_n
        } else {
            A[n * 384 + t] = a + b;           // r / z preacts
        }
    }
    __syncthreads();
    for (int idx = t; idx < 4096; idx += 384) {
        int n = idx >> 7, d = idx & 127;
        int vtx = base + n;
        if (vtx >= N) continue;
        float r = 1.f / (1.f + expf(-A[n * 384 + d]));
        float z = 1.f / (1.f + expf(-A[n * 384 + 128 + d]));
        float nn = tanhf(A[n * 384 + 256 + d] + r * HN[n * 128 + d]);
        float hprev = nf[(size_t)vtx * 128 + d];
        float h = (1.f - z) * nn + z * hprev;
        out[(size_t)vtx * 128 + d] = h > 0.f ? h : 0.f;
    }
}

// ---------------- BatchNorm stats + normalize -----------------------------
__global__ __launch_bounds__(128) void k_bnstats(
    const float* __restrict__ out, float* __restrict__ bn, int N)
{
    int d = threadIdx.x;
    int nb = gridDim.x;
    int rows_per = (N + nb - 1) / nb;
    int r0 = blockIdx.x * rows_per;
    int r1 = min(N, r0 + rows_per);
    float s = 0.f, s2 = 0.f;
    for (int r = r0; r < r1; ++r) {
        float x = out[(size_t)r * 128 + d];
        s += x;
        s2 = fmaf(x, x, s2);
    }
    atomicAdd(&bn[d], s);
    atomicAdd(&bn[128 + d], s2);
}

__global__ __launch_bounds__(256) void k_bnnorm(
    float* __restrict__ out, const float* __restrict__ bn,
    const float* __restrict__ gamma, const float* __restrict__ beta, int N)
{
    int idx = blockIdx.x * 256 + threadIdx.x;
    int total = N * 128;
    if (idx >= total) return;
    int d = idx & 127;
    float invN = 1.f / (float)N;
    float mean = bn[d] * invN;
    float var = bn[128 + d] * invN - mean * mean;
    float inv_std = rsqrtf(var + 1e-5f);
    float x = out[idx];
    out[idx] = (x - mean) * inv_std * gamma[d] + beta[d];
}

// ---------------- host launcher -------------------------------------------
extern "C" void kernel_launch(void* const* d_in, const int* in_sizes, int n_in,
                              void* d_out, int out_size, void* d_ws, size_t ws_size,
                              hipStream_t stream)
{
    const float* nf      = (const float*)d_in[0];
    const int*   src     = (const int*)  d_in[1];
    const int*   dst     = (const int*)  d_in[2];
    const float* W_edge  = (const float*)d_in[3];
    const float* b_edge  = (const float*)d_in[4];
    const float* W_proj  = (const float*)d_in[5];
    const float* b_proj  = (const float*)d_in[6];
    const float* W_ih    = (const float*)d_in[7];
    const float* W_hh    = (const float*)d_in[8];
    const float* b_ih    = (const float*)d_in[9];
    const float* b_hh    = (const float*)d_in[10];
    const float* bn_g    = (const float*)d_in[11];
    const float* bn_b    = (const float*)d_in[12];

    const int N = in_sizes[0] / D;   // 50000
    const int E = in_sizes[1];       // 600000

    float* ws = (float*)d_ws;
    float* s_d       = ws;
    float* s_s       = ws + (size_t)N;
    float* denom     = ws + (size_t)2 * N;
    int*   count     = (int*)(ws + (size_t)3 * N);
    int*   cursor    = (int*)(ws + (size_t)4 * N);
    int*   row_start = (int*)(ws + (size_t)5 * N);
    int*   lex       = (int*)(ws + (size_t)6 * N);
    float* ex        = ws + (size_t)7 * N;
    int*   edge_u    = (int*)(ws + (size_t)7 * N + E);
    float* edge_w    = ws + (size_t)7 * N + (size_t)2 * E;
    float* hv        = ws + (size_t)7 * N + (size_t)3 * E;
    float* W_ihT     = hv + (size_t)N * D;
    float* W_hhT     = W_ihT + 128 * 384;
    float* bn        = W_hhT + 128 * 384;
    // ctx lives in d_out (overwritten later by GRU output rows)
    float* ctx       = (float*)d_out;
    float* outp      = (float*)d_out;

    // zero accumulators: denom (floats) + count (ints) are adjacent
    hipMemsetAsync(denom, 0, (size_t)2 * N * sizeof(float), stream);
    hipMemsetAsync(bn, 0, 256 * sizeof(float), stream);

    int nb_scan = (N + 255) / 256;   // 196 (must be <= 256)

    k_node_scores<<<(N + 3) / 4, 256, 0, stream>>>(nf, W_edge, s_d, s_s, N);
    k_hv<<<(N + 31) / 32, 128, 0, stream>>>(nf, W_proj, b_proj, hv, N);
    k_wt<<<(128 * 384 + 255) / 256, 256, 0, stream>>>(W_ih, W_hh, W_ihT, W_hhT);
    k_edge<<<(E + 255) / 256, 256, 0, stream>>>(src, dst, s_d, s_s, b_edge,
                                                ex, denom, count, E);
    k_scan_local<<<nb_scan, 256, 0, stream>>>(count, lex, (int*)bn + 0, N);
    // NOTE: bsum must not alias bn (bn is float accum) -> use lex tail? give it
    // its own slot right after bn:
    // (fixed below by separate pointer)
    k_scan_local<<<1, 1, 0, stream>>>(count, lex, (int*)bn, 0); // no-op guard
    // proper scan buffers:
    {
        int* bsum = (int*)(bn + 256);
        k_scan_local<<<nb_scan, 256, 0, stream>>>(count, lex, bsum, N);
        k_scan_blocks<<<1, 256, 0, stream>>>(bsum, nb_scan);
        k_scan_apply<<<nb_scan, 256, 0, stream>>>(lex, bsum, row_start, cursor, N);
    }
    k_fill<<<(E + 255) / 256, 256, 0, stream>>>(src, dst, ex, denom, cursor,
                                                edge_u, edge_w, E);
    k_agg<<<N, 128, 0, stream>>>(hv, row_start, count, edge_u, edge_w, ctx, N);
    k_gru<<<(N + 31) / 32, 384, 0, stream>>>(ctx, nf, W_ihT, W_hhT, b_ih, b_hh,
                                             outp, N);
    k_bnstats<<<256, 128, 0, stream>>>(outp, bn, N);
    k_bnnorm<<<(N * D + 255) / 256, 256, 0, stream>>>(outp, bn, bn_g, bn_b, N);
}

// Round 2
// 353.026 us; speedup vs baseline: 2.0515x; 2.0515x over previous
//
#include <hip/hip_runtime.h>
#include <math.h>

constexpr int D = 128;

typedef __attribute__((ext_vector_type(8))) short short8;
typedef __attribute__((ext_vector_type(4))) float f32x4;
typedef unsigned short ushort_t;
typedef unsigned int uint_t;

__device__ inline ushort_t f2b(float x) {          // fp32 -> bf16 RNE
    uint_t u = __float_as_uint(x);
    uint_t r = u + 0x7fffu + ((u >> 16) & 1u);
    return (ushort_t)(r >> 16);
}
__device__ inline float b2f(ushort_t b) { return __uint_as_float(((uint_t)b) << 16); }

__device__ inline float sigm(float x) { return 1.f / (1.f + __expf(-x)); }
__device__ inline float tanh_(float x) {
    float t = __expf(-2.f * fabsf(x));            // no overflow
    float y = (1.f - t) / (1.f + t);
    return x >= 0.f ? y : -y;
}

// ---- convert weights to bf16 (W_ih/W_hh native [out][k]; W_proj transposed)
__global__ __launch_bounds__(256) void k_prep_w(
    const float* __restrict__ W_ih, const float* __restrict__ W_hh,
    const float* __restrict__ W_proj,
    ushort_t* __restrict__ Wih16, ushort_t* __restrict__ Whh16,
    ushort_t* __restrict__ WpT16)
{
    int idx = blockIdx.x * 256 + threadIdx.x;
    if (idx < 49152) {
        Wih16[idx] = f2b(W_ih[idx]);
    } else if (idx < 98304) {
        int i = idx - 49152;
        Whh16[i] = f2b(W_hh[i]);
    } else if (idx < 114688) {
        int t = idx - 98304;           // t = j*128 + k ; WpT[j][k] = W_proj[k][j]
        int j = t >> 7, k = t & 127;
        WpT16[t] = f2b(W_proj[k * 128 + j]);
    }
}

// ---- nf -> bf16 copy + per-node edge score components (fused) -------------
__global__ __launch_bounds__(256) void k_cvt_scores(
    const float* __restrict__ nf, const float* __restrict__ W_edge,
    ushort_t* __restrict__ nf16, float* __restrict__ s_d,
    float* __restrict__ s_s, int N)
{
    int wave = threadIdx.x >> 6, lane = threadIdx.x & 63;
    int v = blockIdx.x * 4 + wave;
    if (v >= N) return;
    float2 f = *(const float2*)(nf + (size_t)v * 128 + 2 * lane);
    uint_t packed = (uint_t)f2b(f.x) | ((uint_t)f2b(f.y) << 16);
    ((uint_t*)nf16)[(size_t)v * 64 + lane] = packed;
    float pd = f.x * W_edge[2 * lane] + f.y * W_edge[2 * lane + 1];
    float ps = f.x * W_edge[128 + 2 * lane] + f.y * W_edge[128 + 2 * lane + 1];
#pragma unroll
    for (int off = 32; off; off >>= 1) {
        pd += __shfl_down(pd, off);
        ps += __shfl_down(ps, off);
    }
    if (lane == 0) { s_d[v] = pd; s_s[v] = ps; }
}

// ---- hv16 = bf16(nf16 @ W_projT + b_proj)  (MFMA, no LDS) ----------------
__global__ __launch_bounds__(256) void k_hv_mfma(
    const ushort_t* __restrict__ nf16, const ushort_t* __restrict__ WpT16,
    const float* __restrict__ b_proj, ushort_t* __restrict__ hv16, int N)
{
    int w = threadIdx.x >> 6, lane = threadIdx.x & 63;
    int r0 = blockIdx.x * 64 + w * 16;
    int am = lane & 15, ak = (lane >> 4) * 8;
    int arow = r0 + am;
    bool aok = arow < N;
    short8 A[4];
#pragma unroll
    for (int kf = 0; kf < 4; ++kf) {
        short8 z = {0,0,0,0,0,0,0,0};
        A[kf] = aok ? *(const short8*)(nf16 + (size_t)arow * 128 + kf * 32 + ak) : z;
    }
    int crow0 = r0 + (lane >> 4) * 4;
#pragma unroll
    for (int nc = 0; nc < 8; ++nc) {
        f32x4 acc = {0.f, 0.f, 0.f, 0.f};
        int col = nc * 16 + am;
#pragma unroll
        for (int kf = 0; kf < 4; ++kf) {
            short8 B = *(const short8*)(WpT16 + (size_t)col * 128 + kf * 32 + ak);
            acc = __builtin_amdgcn_mfma_f32_16x16x32_bf16(A[kf], B, acc, 0, 0, 0);
        }
        float b = b_proj[col];
#pragma unroll
        for (int r = 0; r < 4; ++r) {
            int grow = crow0 + r;
            if (grow < N) hv16[(size_t)grow * 128 + col] = f2b(acc[r] + b);
        }
    }
}

// ---- per-edge exp(leaky) + denom + counts --------------------------------
__global__ void k_edge(
    const int* __restrict__ src, const int* __restrict__ dst,
    const float* __restrict__ s_d, const float* __restrict__ s_s,
    const float* __restrict__ b_edge, float* __restrict__ ex,
    float* __restrict__ denom, int* __restrict__ count, int E)
{
    int e = blockIdx.x * blockDim.x + threadIdx.x;
    if (e >= E) return;
    int s = src[e], t = dst[e];
    float l = s_d[t] + s_s[s] + b_edge[0];
    l = l > 0.f ? l : 0.01f * l;
    float ev = __expf(l);
    ex[e] = ev;
    atomicAdd(&denom[t], ev);
    atomicAdd(&count[t], 1);
}

// ---- 3-phase scan for CSR row offsets ------------------------------------
__global__ __launch_bounds__(256) void k_scan_local(
    const int* __restrict__ count, int* __restrict__ lex,
    int* __restrict__ bsum, int N)
{
    __shared__ int sdata[256];
    int tid = threadIdx.x;
    int i = blockIdx.x * 256 + tid;
    int v = (i < N) ? count[i] : 0;
    int incl = v;
    sdata[tid] = incl; __syncthreads();
#pragma unroll
    for (int off = 1; off < 256; off <<= 1) {
        int add = (tid >= off) ? sdata[tid - off] : 0;
        __syncthreads();
        incl += add;
        sdata[tid] = incl;
        __syncthreads();
    }
    if (i < N) lex[i] = incl - v;
    if (tid == 255) bsum[blockIdx.x] = incl;
}

__global__ __launch_bounds__(256) void k_scan_blocks(int* __restrict__ bsum, int nb)
{
    __shared__ int sdata[256];
    int tid = threadIdx.x;
    int v = (tid < nb) ? bsum[tid] : 0;
    int incl = v;
    sdata[tid] = incl; __syncthreads();
#pragma unroll
    for (int off = 1; off < 256; off <<= 1) {
        int add = (tid >= off) ? sdata[tid - off] : 0;
        __syncthreads();
        incl += add;
        sdata[tid] = incl;
        __syncthreads();
    }
    if (tid < nb) bsum[tid] = incl - v;   // exclusive
}

__global__ __launch_bounds__(256) void k_scan_apply(
    const int* __restrict__ lex, const int* __restrict__ bsum,
    int* __restrict__ row_start, int* __restrict__ cursor, int N)
{
    int i = blockIdx.x * 256 + threadIdx.x;
    if (i < N) {
        int o = lex[i] + bsum[blockIdx.x];
        row_start[i] = o;
        cursor[i] = o;
    }
}

// ---- fill CSR with pre-divided weights (a+1) -----------------------------
__global__ void k_fill(
    const int* __restrict__ src, const int* __restrict__ dst,
    const float* __restrict__ ex, const float* __restrict__ denom,
    int* __restrict__ cursor, int* __restrict__ edge_u,
    float* __restrict__ edge_w, int E)
{
    int e = blockIdx.x * blockDim.x + threadIdx.x;
    if (e >= E) return;
    int t = dst[e];
    int pos = atomicAdd(&cursor[t], 1);
    edge_u[pos] = src[e];
    edge_w[pos] = ex[e] / denom[t] + 1.0f;
}

// ---- aggregate: ctx16[v] = bf16(elu(sum hv16[u]*w)) ----------------------
__global__ __launch_bounds__(256) void k_agg2(
    const ushort_t* __restrict__ hv16, const int* __restrict__ row_start,
    const int* __restrict__ count, const int* __restrict__ edge_u,
    const float* __restrict__ edge_w, ushort_t* __restrict__ ctx16, int N)
{
    int w = threadIdx.x >> 6, lane = threadIdx.x & 63;
    int v = blockIdx.x * 4 + w;
    if (v >= N) return;
    int beg = row_start[v], cnt = count[v];
    float a0 = 0.f, a1 = 0.f;
    int i = 0;
    for (; i + 2 <= cnt; i += 2) {
        int u0 = edge_u[beg + i], u1 = edge_u[beg + i + 1];
        float w0 = edge_w[beg + i], w1 = edge_w[beg + i + 1];
        uint_t p0 = *(const uint_t*)(hv16 + (size_t)u0 * 128 + 2 * lane);
        uint_t p1 = *(const uint_t*)(hv16 + (size_t)u1 * 128 + 2 * lane);
        a0 = fmaf(b2f((ushort_t)p0), w0, a0);
        a1 = fmaf(b2f((ushort_t)(p0 >> 16)), w0, a1);
        a0 = fmaf(b2f((ushort_t)p1), w1, a0);
        a1 = fmaf(b2f((ushort_t)(p1 >> 16)), w1, a1);
    }
    if (i < cnt) {
        int u = edge_u[beg + i];
        float wt = edge_w[beg + i];
        uint_t p = *(const uint_t*)(hv16 + (size_t)u * 128 + 2 * lane);
        a0 = fmaf(b2f((ushort_t)p), wt, a0);
        a1 = fmaf(b2f((ushort_t)(p >> 16)), wt, a1);
    }
    a0 = a0 > 0.f ? a0 : expm1f(a0);
    a1 = a1 > 0.f ? a1 : expm1f(a1);
    uint_t packed = (uint_t)f2b(a0) | ((uint_t)f2b(a1) << 16);
    ((uint_t*)ctx16)[(size_t)v * 64 + lane] = packed;
}

// ---- fused GRU: both gate GEMMs (MFMA) + elementwise + relu --------------
__global__ __launch_bounds__(256) void k_gru_mfma(
    const ushort_t* __restrict__ ctx16, const ushort_t* __restrict__ nf16,
    const float* __restrict__ nf,
    const ushort_t* __restrict__ Wih16, const ushort_t* __restrict__ Whh16,
    const float* __restrict__ b_ih, const float* __restrict__ b_hh,
    float* __restrict__ out, int N)
{
    int w = threadIdx.x >> 6, lane = threadIdx.x & 63;
    int r0 = blockIdx.x * 64 + w * 16;
    int am = lane & 15, ak = (lane >> 4) * 8;
    int arow = r0 + am;
    bool aok = arow < N;
    short8 Ac[4], An[4];
#pragma unroll
    for (int kf = 0; kf < 4; ++kf) {
        short8 z = {0,0,0,0,0,0,0,0};
        size_t off = (size_t)arow * 128 + kf * 32 + ak;
        Ac[kf] = aok ? *(const short8*)(ctx16 + off) : z;
        An[kf] = aok ? *(const short8*)(nf16 + off) : z;
    }
    int crow0 = r0 + (lane >> 4) * 4;
#pragma unroll 1
    for (int c = 0; c < 8; ++c) {
        int d = c * 16 + am;                      // output dim 0..127
        f32x4 racc = {0.f,0.f,0.f,0.f}, zacc = {0.f,0.f,0.f,0.f};
        f32x4 iacc = {0.f,0.f,0.f,0.f}, hacc = {0.f,0.f,0.f,0.f};
#pragma unroll
        for (int kf = 0; kf < 4; ++kf) {
            int ko = kf * 32 + ak;
            short8 Br = *(const short8*)(Wih16 + (size_t)d * 128 + ko);
            short8 Cr = *(const short8*)(Whh16 + (size_t)d * 128 + ko);
            short8 Bz = *(const short8*)(Wih16 + (size_t)(128 + d) * 128 + ko);
            short8 Cz = *(const short8*)(Whh16 + (size_t)(128 + d) * 128 + ko);
            short8 Bi = *(const short8*)(Wih16 + (size_t)(256 + d) * 128 + ko);
            short8 Ch = *(const short8*)(Whh16 + (size_t)(256 + d) * 128 + ko);
            racc = __builtin_amdgcn_mfma_f32_16x16x32_bf16(Ac[kf], Br, racc, 0, 0, 0);
            racc = __builtin_amdgcn_mfma_f32_16x16x32_bf16(An[kf], Cr, racc, 0, 0, 0);
            zacc = __builtin_amdgcn_mfma_f32_16x16x32_bf16(Ac[kf], Bz, zacc, 0, 0, 0);
            zacc = __builtin_amdgcn_mfma_f32_16x16x32_bf16(An[kf], Cz, zacc, 0, 0, 0);
            iacc = __builtin_amdgcn_mfma_f32_16x16x32_bf16(Ac[kf], Bi, iacc, 0, 0, 0);
            hacc = __builtin_amdgcn_mfma_f32_16x16x32_bf16(An[kf], Ch, hacc, 0, 0, 0);
        }
        float br = b_ih[d] + b_hh[d];
        float bz = b_ih[128 + d] + b_hh[128 + d];
        float bi = b_ih[256 + d];
        float bh = b_hh[256 + d];
#pragma unroll
        for (int r = 0; r < 4; ++r) {
            int grow = crow0 + r;
            if (grow >= N) continue;
            float rv = sigm(racc[r] + br);
            float zv = sigm(zacc[r] + bz);
            float nv = tanh_(iacc[r] + bi + rv * (hacc[r] + bh));
            float hp = nf[(size_t)grow * 128 + d];
            float h = (1.f - zv) * nv + zv * hp;
            out[(size_t)grow * 128 + d] = fmaxf(h, 0.f);
        }
    }
}

// ---- BatchNorm stats + normalize -----------------------------------------
__global__ __launch_bounds__(128) void k_bnstats(
    const float* __restrict__ out, float* __restrict__ bn, int N)
{
    int d = threadIdx.x;
    int nb = gridDim.x;
    int rows_per = (N + nb - 1) / nb;
    int r0 = blockIdx.x * rows_per;
    int r1 = min(N, r0 + rows_per);
    float s = 0.f, s2 = 0.f;
    for (int r = r0; r < r1; ++r) {
        float x = out[(size_t)r * 128 + d];
        s += x;
        s2 = fmaf(x, x, s2);
    }
    atomicAdd(&bn[d], s);
    atomicAdd(&bn[128 + d], s2);
}

__global__ __launch_bounds__(256) void k_bnnorm(
    float* __restrict__ out, const float* __restrict__ bn,
    const float* __restrict__ gamma, const float* __restrict__ beta, int N)
{
    int idx = blockIdx.x * 256 + threadIdx.x;
    int total = N * 128;
    if (idx >= total) return;
    int d = idx & 127;
    float invN = 1.f / (float)N;
    float mean = bn[d] * invN;
    float var = bn[128 + d] * invN - mean * mean;
    float inv_std = rsqrtf(var + 1e-5f);
    float x = out[idx];
    out[idx] = (x - mean) * inv_std * gamma[d] + beta[d];
}

// ---- host launcher -------------------------------------------------------
extern "C" void kernel_launch(void* const* d_in, const int* in_sizes, int n_in,
                              void* d_out, int out_size, void* d_ws, size_t ws_size,
                              hipStream_t stream)
{
    const float* nf     = (const float*)d_in[0];
    const int*   src    = (const int*)  d_in[1];
    const int*   dst    = (const int*)  d_in[2];
    const float* W_edge = (const float*)d_in[3];
    const float* b_edge = (const float*)d_in[4];
    const float* W_proj = (const float*)d_in[5];
    const float* b_proj = (const float*)d_in[6];
    const float* W_ih   = (const float*)d_in[7];
    const float* W_hh   = (const float*)d_in[8];
    const float* b_ih   = (const float*)d_in[9];
    const float* b_hh   = (const float*)d_in[10];
    const float* bn_g   = (const float*)d_in[11];
    const float* bn_b   = (const float*)d_in[12];

    const int N = in_sizes[0] / D;   // 50000
    const int E = in_sizes[1];       // 600000

    float* ws = (float*)d_ws;
    float* s_d       = ws;
    float* s_s       = ws + (size_t)N;
    float* denom     = ws + (size_t)2 * N;
    int*   count     = (int*)(ws + (size_t)3 * N);
    int*   cursor    = (int*)(ws + (size_t)4 * N);
    int*   row_start = (int*)(ws + (size_t)5 * N);
    int*   lex       = (int*)(ws + (size_t)6 * N);
    float* ex        = ws + (size_t)7 * N;
    int*   edge_u    = (int*)(ex + (size_t)E);
    float* edge_w    = ex + (size_t)2 * E;
    float* bn        = ex + (size_t)3 * E;
    int*   bsum      = (int*)(bn + 256);
    ushort_t* nf16   = (ushort_t*)(bn + 512);          // 16B-aligned
    ushort_t* hv16   = nf16 + (size_t)N * 128;
    ushort_t* ctx16  = hv16 + (size_t)N * 128;
    ushort_t* Wih16  = ctx16 + (size_t)N * 128;
    ushort_t* Whh16  = Wih16 + 384 * 128;
    ushort_t* WpT16  = Whh16 + 384 * 128;

    float* outp = (float*)d_out;

    hipMemsetAsync(denom, 0, (size_t)2 * N * sizeof(float), stream);  // denom+count
    hipMemsetAsync(bn, 0, 256 * sizeof(float), stream);

    int nb_scan = (N + 255) / 256;   // 196 <= 256

    k_prep_w<<<(114688 + 255) / 256, 256, 0, stream>>>(W_ih, W_hh, W_proj,
                                                       Wih16, Whh16, WpT16);
    k_cvt_scores<<<(N + 3) / 4, 256, 0, stream>>>(nf, W_edge, nf16, s_d, s_s, N);
    k_hv_mfma<<<(N + 63) / 64, 256, 0, stream>>>(nf16, WpT16, b_proj, hv16, N);
    k_edge<<<(E + 255) / 256, 256, 0, stream>>>(src, dst, s_d, s_s, b_edge,
                                                ex, denom, count, E);
    k_scan_local<<<nb_scan, 256, 0, stream>>>(count, lex, bsum, N);
    k_scan_blocks<<<1, 256, 0, stream>>>(bsum, nb_scan);
    k_scan_apply<<<nb_scan, 256, 0, stream>>>(lex, bsum, row_start, cursor, N);
    k_fill<<<(E + 255) / 256, 256, 0, stream>>>(src, dst, ex, denom, cursor,
                                                edge_u, edge_w, E);
    k_agg2<<<(N + 3) / 4, 256, 0, stream>>>(hv16, row_start, count, edge_u,
                                            edge_w, ctx16, N);
    k_gru_mfma<<<(N + 63) / 64, 256, 0, stream>>>(ctx16, nf16, nf, Wih16, Whh16,
                                                  b_ih, b_hh, outp, N);
    k_bnstats<<<256, 128, 0, stream>>>(outp, bn, N);
    k_bnnorm<<<(N * D + 255) / 256, 256, 0, stream>>>(outp, bn, bn_g, bn_b, N);
}

// Round 3
// 323.286 us; speedup vs baseline: 2.2402x; 1.0920x over previous
//
#include <hip/hip_runtime.h>
#include <math.h>

constexpr int D = 128;

typedef __attribute__((ext_vector_type(8))) short short8;
typedef __attribute__((ext_vector_type(4))) float f32x4;
typedef unsigned short ushort_t;
typedef unsigned int uint_t;

__device__ inline ushort_t f2b(float x) {          // fp32 -> bf16 RNE
    uint_t u = __float_as_uint(x);
    uint_t r = u + 0x7fffu + ((u >> 16) & 1u);
    return (ushort_t)(r >> 16);
}
__device__ inline float b2f(ushort_t b) { return __uint_as_float(((uint_t)b) << 16); }

__device__ inline float sigm(float x) { return 1.f / (1.f + __expf(-x)); }
__device__ inline float tanh_(float x) {
    float t = __expf(-2.f * fabsf(x));
    float y = (1.f - t) / (1.f + t);
    return x >= 0.f ? y : -y;
}

// ---- convert weights to bf16 ---------------------------------------------
__global__ __launch_bounds__(256) void k_prep_w(
    const float* __restrict__ W_ih, const float* __restrict__ W_hh,
    const float* __restrict__ W_proj,
    ushort_t* __restrict__ Wih16, ushort_t* __restrict__ Whh16,
    ushort_t* __restrict__ WpT16)
{
    int idx = blockIdx.x * 256 + threadIdx.x;
    if (idx < 49152) {
        Wih16[idx] = f2b(W_ih[idx]);
    } else if (idx < 98304) {
        int i = idx - 49152;
        Whh16[i] = f2b(W_hh[i]);
    } else if (idx < 114688) {
        int t = idx - 98304;           // WpT[j][k] = W_proj[k][j]
        int j = t >> 7, k = t & 127;
        WpT16[t] = f2b(W_proj[k * 128 + j]);
    }
}

// ---- fused: nf->bf16, edge scores, hv = nf@WpT+b (MFMA) ------------------
__global__ __launch_bounds__(256) void k_hv_fused(
    const float* __restrict__ nf, const ushort_t* __restrict__ WpT16,
    const float* __restrict__ b_proj, const float* __restrict__ W_edge,
    ushort_t* __restrict__ nf16, ushort_t* __restrict__ hv16,
    float* __restrict__ s_d, float* __restrict__ s_s, int N)
{
    int w = threadIdx.x >> 6, lane = threadIdx.x & 63;
    int r0 = blockIdx.x * 64 + w * 16;
    int am = lane & 15, hi = lane >> 4, ak = hi * 8;
    int arow = r0 + am;
    bool aok = arow < N;
    short8 A[4];
    float pd = 0.f, ps = 0.f;
#pragma unroll
    for (int kf = 0; kf < 4; ++kf) {
        int ko = kf * 32 + ak;
        float4 f0 = {0,0,0,0}, f1 = {0,0,0,0};
        if (aok) {
            f0 = *(const float4*)(nf + (size_t)arow * 128 + ko);
            f1 = *(const float4*)(nf + (size_t)arow * 128 + ko + 4);
        }
        pd += f0.x * W_edge[ko]     + f0.y * W_edge[ko + 1]
            + f0.z * W_edge[ko + 2] + f0.w * W_edge[ko + 3]
            + f1.x * W_edge[ko + 4] + f1.y * W_edge[ko + 5]
            + f1.z * W_edge[ko + 6] + f1.w * W_edge[ko + 7];
        ps += f0.x * W_edge[128+ko]     + f0.y * W_edge[128+ko+1]
            + f0.z * W_edge[128+ko+2]   + f0.w * W_edge[128+ko+3]
            + f1.x * W_edge[128+ko+4]   + f1.y * W_edge[128+ko+5]
            + f1.z * W_edge[128+ko+6]   + f1.w * W_edge[128+ko+7];
        short8 a;
        a[0] = (short)f2b(f0.x); a[1] = (short)f2b(f0.y);
        a[2] = (short)f2b(f0.z); a[3] = (short)f2b(f0.w);
        a[4] = (short)f2b(f1.x); a[5] = (short)f2b(f1.y);
        a[6] = (short)f2b(f1.z); a[7] = (short)f2b(f1.w);
        A[kf] = a;
        if (aok) *(short8*)(nf16 + (size_t)arow * 128 + ko) = a;
    }
    // reduce scores over the 4 lanes holding the same row
    pd += __shfl_xor(pd, 16); pd += __shfl_xor(pd, 32);
    ps += __shfl_xor(ps, 16); ps += __shfl_xor(ps, 32);
    if (hi == 0 && aok) { s_d[arow] = pd; s_s[arow] = ps; }

    int crow0 = r0 + hi * 4;
#pragma unroll
    for (int nc = 0; nc < 8; ++nc) {
        f32x4 acc = {0.f, 0.f, 0.f, 0.f};
        int col = nc * 16 + am;
#pragma unroll
        for (int kf = 0; kf < 4; ++kf) {
            short8 B = *(const short8*)(WpT16 + (size_t)col * 128 + kf * 32 + ak);
            acc = __builtin_amdgcn_mfma_f32_16x16x32_bf16(A[kf], B, acc, 0, 0, 0);
        }
        float b = b_proj[col];
#pragma unroll
        for (int r = 0; r < 4; ++r) {
            int grow = crow0 + r;
            if (grow < N) hv16[(size_t)grow * 128 + col] = f2b(acc[r] + b);
        }
    }
}

// ---- pass 1 over edges: denom + count atomics ----------------------------
__global__ void k_edge(
    const int* __restrict__ src, const int* __restrict__ dst,
    const float* __restrict__ s_d, const float* __restrict__ s_s,
    const float* __restrict__ b_edge,
    float* __restrict__ denom, int* __restrict__ count, int E)
{
    int e = blockIdx.x * blockDim.x + threadIdx.x;
    if (e >= E) return;
    int s = src[e], t = dst[e];
    float l = s_d[t] + s_s[s] + b_edge[0];
    l = l > 0.f ? l : 0.01f * l;
    float ev = __expf(l);
    atomicAdd(&denom[t], ev);
    atomicAdd(&count[t], 1);
}

// ---- 3-phase scan for CSR row offsets ------------------------------------
__global__ __launch_bounds__(256) void k_scan_local(
    const int* __restrict__ count, int* __restrict__ lex,
    int* __restrict__ bsum, int N)
{
    __shared__ int sdata[256];
    int tid = threadIdx.x;
    int i = blockIdx.x * 256 + tid;
    int v = (i < N) ? count[i] : 0;
    int incl = v;
    sdata[tid] = incl; __syncthreads();
#pragma unroll
    for (int off = 1; off < 256; off <<= 1) {
        int add = (tid >= off) ? sdata[tid - off] : 0;
        __syncthreads();
        incl += add;
        sdata[tid] = incl;
        __syncthreads();
    }
    if (i < N) lex[i] = incl - v;
    if (tid == 255) bsum[blockIdx.x] = incl;
}

__global__ __launch_bounds__(256) void k_scan_blocks(int* __restrict__ bsum, int nb)
{
    __shared__ int sdata[256];
    int tid = threadIdx.x;
    int v = (tid < nb) ? bsum[tid] : 0;
    int incl = v;
    sdata[tid] = incl; __syncthreads();
#pragma unroll
    for (int off = 1; off < 256; off <<= 1) {
        int add = (tid >= off) ? sdata[tid - off] : 0;
        __syncthreads();
        incl += add;
        sdata[tid] = incl;
        __syncthreads();
    }
    if (tid < nb) bsum[tid] = incl - v;   // exclusive
}

__global__ __launch_bounds__(256) void k_scan_apply(
    const int* __restrict__ lex, const int* __restrict__ bsum,
    int* __restrict__ row_start, int* __restrict__ cursor, int N)
{
    int i = blockIdx.x * 256 + threadIdx.x;
    if (i < N) {
        int o = lex[i] + bsum[blockIdx.x];
        row_start[i] = o;
        cursor[i] = o;
    }
}

// ---- pass 2: fill CSR (edge_w = raw exp; division deferred to agg) -------
__global__ void k_fill(
    const int* __restrict__ src, const int* __restrict__ dst,
    const float* __restrict__ s_d, const float* __restrict__ s_s,
    const float* __restrict__ b_edge,
    int* __restrict__ cursor, int* __restrict__ edge_u,
    float* __restrict__ edge_w, int E)
{
    int e = blockIdx.x * blockDim.x + threadIdx.x;
    if (e >= E) return;
    int s = src[e], t = dst[e];
    float l = s_d[t] + s_s[s] + b_edge[0];
    l = l > 0.f ? l : 0.01f * l;
    float ev = __expf(l);
    int pos = atomicAdd(&cursor[t], 1);
    edge_u[pos] = s;
    edge_w[pos] = ev;
}

// ---- aggregate: ctx = elu(num/denom + one_sum) ---------------------------
__global__ __launch_bounds__(256) void k_agg2(
    const ushort_t* __restrict__ hv16, const int* __restrict__ row_start,
    const int* __restrict__ count, const float* __restrict__ denom,
    const int* __restrict__ edge_u, const float* __restrict__ edge_w,
    ushort_t* __restrict__ ctx16, int N)
{
    int w = threadIdx.x >> 6, lane = threadIdx.x & 63;
    int v = blockIdx.x * 4 + w;
    if (v >= N) return;
    int beg = row_start[v], cnt = count[v];
    float num0 = 0.f, num1 = 0.f, one0 = 0.f, one1 = 0.f;
    for (int chunk = 0; chunk < cnt; chunk += 64) {
        int m = min(64, cnt - chunk);
        int uu = 0; float ww = 0.f;
        if (lane < m) {
            uu = edge_u[beg + chunk + lane];
            ww = edge_w[beg + chunk + lane];
        }
        for (int i = 0; i < m; ++i) {
            int u = __shfl(uu, i);
            float ev = __shfl(ww, i);
            uint_t p = ((const uint_t*)(hv16 + (size_t)u * 128))[lane];
            float h0 = b2f((ushort_t)p);
            float h1 = b2f((ushort_t)(p >> 16));
            num0 = fmaf(h0, ev, num0);
            num1 = fmaf(h1, ev, num1);
            one0 += h0;
            one1 += h1;
        }
    }
    float c0 = 0.f, c1 = 0.f;
    if (cnt > 0) {
        float inv = 1.f / denom[v];
        c0 = num0 * inv + one0;
        c1 = num1 * inv + one1;
    }
    c0 = c0 > 0.f ? c0 : expm1f(c0);
    c1 = c1 > 0.f ? c1 : expm1f(c1);
    uint_t packed = (uint_t)f2b(c0) | ((uint_t)f2b(c1) << 16);
    ((uint_t*)ctx16)[(size_t)v * 64 + lane] = packed;
}

// ---- fused GRU: 32 rows/wave, both gate GEMMs + elementwise + relu -------
__global__ __launch_bounds__(256) void k_gru_mfma(
    const ushort_t* __restrict__ ctx16, const ushort_t* __restrict__ nf16,
    const float* __restrict__ nf,
    const ushort_t* __restrict__ Wih16, const ushort_t* __restrict__ Whh16,
    const float* __restrict__ b_ih, const float* __restrict__ b_hh,
    float* __restrict__ out, int N)
{
    int w = threadIdx.x >> 6, lane = threadIdx.x & 63;
    int r0 = blockIdx.x * 128 + w * 32;
    int am = lane & 15, hi = lane >> 4, ak = hi * 8;
    short8 Ac[2][4], An[2][4];
#pragma unroll
    for (int rf = 0; rf < 2; ++rf) {
        int arow = r0 + rf * 16 + am;
        bool aok = arow < N;
        short8 z = {0,0,0,0,0,0,0,0};
#pragma unroll
        for (int kf = 0; kf < 4; ++kf) {
            size_t off = (size_t)arow * 128 + kf * 32 + ak;
            Ac[rf][kf] = aok ? *(const short8*)(ctx16 + off) : z;
            An[rf][kf] = aok ? *(const short8*)(nf16 + off) : z;
        }
    }
#pragma unroll 1
    for (int c = 0; c < 8; ++c) {
        int d = c * 16 + am;
        f32x4 racc[2], zacc[2], iacc[2], hacc[2];
#pragma unroll
        for (int rf = 0; rf < 2; ++rf) {
            racc[rf] = (f32x4){0.f,0.f,0.f,0.f};
            zacc[rf] = (f32x4){0.f,0.f,0.f,0.f};
            iacc[rf] = (f32x4){0.f,0.f,0.f,0.f};
            hacc[rf] = (f32x4){0.f,0.f,0.f,0.f};
        }
#pragma unroll
        for (int kf = 0; kf < 4; ++kf) {
            int ko = kf * 32 + ak;
            short8 Br = *(const short8*)(Wih16 + (size_t)d * 128 + ko);
            short8 Cr = *(const short8*)(Whh16 + (size_t)d * 128 + ko);
            short8 Bz = *(const short8*)(Wih16 + (size_t)(128 + d) * 128 + ko);
            short8 Cz = *(const short8*)(Whh16 + (size_t)(128 + d) * 128 + ko);
            short8 Bi = *(const short8*)(Wih16 + (size_t)(256 + d) * 128 + ko);
            short8 Ch = *(const short8*)(Whh16 + (size_t)(256 + d) * 128 + ko);
#pragma unroll
            for (int rf = 0; rf < 2; ++rf) {
                racc[rf] = __builtin_amdgcn_mfma_f32_16x16x32_bf16(Ac[rf][kf], Br, racc[rf], 0, 0, 0);
                racc[rf] = __builtin_amdgcn_mfma_f32_16x16x32_bf16(An[rf][kf], Cr, racc[rf], 0, 0, 0);
                zacc[rf] = __builtin_amdgcn_mfma_f32_16x16x32_bf16(Ac[rf][kf], Bz, zacc[rf], 0, 0, 0);
                zacc[rf] = __builtin_amdgcn_mfma_f32_16x16x32_bf16(An[rf][kf], Cz, zacc[rf], 0, 0, 0);
                iacc[rf] = __builtin_amdgcn_mfma_f32_16x16x32_bf16(Ac[rf][kf], Bi, iacc[rf], 0, 0, 0);
                hacc[rf] = __builtin_amdgcn_mfma_f32_16x16x32_bf16(An[rf][kf], Ch, hacc[rf], 0, 0, 0);
            }
        }
        float br = b_ih[d] + b_hh[d];
        float bz = b_ih[128 + d] + b_hh[128 + d];
        float bi = b_ih[256 + d];
        float bh = b_hh[256 + d];
#pragma unroll
        for (int rf = 0; rf < 2; ++rf) {
            int crow0 = r0 + rf * 16 + hi * 4;
#pragma unroll
            for (int r = 0; r < 4; ++r) {
                int grow = crow0 + r;
                if (grow >= N) continue;
                float rv = sigm(racc[rf][r] + br);
                float zv = sigm(zacc[rf][r] + bz);
                float nv = tanh_(iacc[rf][r] + bi + rv * (hacc[rf][r] + bh));
                float hp = nf[(size_t)grow * 128 + d];
                float h = (1.f - zv) * nv + zv * hp;
                out[(size_t)grow * 128 + d] = fmaxf(h, 0.f);
            }
        }
    }
}

// ---- BatchNorm stats + normalize -----------------------------------------
__global__ __launch_bounds__(128) void k_bnstats(
    const float* __restrict__ out, float* __restrict__ bn, int N)
{
    int d = threadIdx.x;
    int nb = gridDim.x;
    int rows_per = (N + nb - 1) / nb;
    int r0 = blockIdx.x * rows_per;
    int r1 = min(N, r0 + rows_per);
    float s = 0.f, s2 = 0.f;
    for (int r = r0; r < r1; ++r) {
        float x = out[(size_t)r * 128 + d];
        s += x;
        s2 = fmaf(x, x, s2);
    }
    atomicAdd(&bn[d], s);
    atomicAdd(&bn[128 + d], s2);
}

__global__ __launch_bounds__(256) void k_bnnorm(
    float* __restrict__ out, const float* __restrict__ bn,
    const float* __restrict__ gamma, const float* __restrict__ beta, int N)
{
    int idx = blockIdx.x * 256 + threadIdx.x;
    int total = N * 128;
    if (idx >= total) return;
    int d = idx & 127;
    float invN = 1.f / (float)N;
    float mean = bn[d] * invN;
    float var = bn[128 + d] * invN - mean * mean;
    float inv_std = rsqrtf(var + 1e-5f);
    float x = out[idx];
    out[idx] = (x - mean) * inv_std * gamma[d] + beta[d];
}

// ---- host launcher -------------------------------------------------------
extern "C" void kernel_launch(void* const* d_in, const int* in_sizes, int n_in,
                              void* d_out, int out_size, void* d_ws, size_t ws_size,
                              hipStream_t stream)
{
    const float* nf     = (const float*)d_in[0];
    const int*   src    = (const int*)  d_in[1];
    const int*   dst    = (const int*)  d_in[2];
    const float* W_edge = (const float*)d_in[3];
    const float* b_edge = (const float*)d_in[4];
    const float* W_proj = (const float*)d_in[5];
    const float* b_proj = (const float*)d_in[6];
    const float* W_ih   = (const float*)d_in[7];
    const float* W_hh   = (const float*)d_in[8];
    const float* b_ih   = (const float*)d_in[9];
    const float* b_hh   = (const float*)d_in[10];
    const float* bn_g   = (const float*)d_in[11];
    const float* bn_b   = (const float*)d_in[12];

    const int N = in_sizes[0] / D;   // 50000
    const int E = in_sizes[1];       // 600000

    float* ws = (float*)d_ws;
    float* s_d       = ws;
    float* s_s       = ws + (size_t)N;
    float* denom     = ws + (size_t)2 * N;
    int*   count     = (int*)(ws + (size_t)3 * N);
    int*   cursor    = (int*)(ws + (size_t)4 * N);
    int*   row_start = (int*)(ws + (size_t)5 * N);
    int*   lex       = (int*)(ws + (size_t)6 * N);
    int*   edge_u    = (int*)(ws + (size_t)7 * N);
    float* edge_w    = ws + (size_t)7 * N + (size_t)E;
    float* bn        = ws + (size_t)7 * N + (size_t)2 * E;
    int*   bsum      = (int*)(bn + 256);
    ushort_t* nf16   = (ushort_t*)(bn + 512);
    ushort_t* hv16   = nf16 + (size_t)N * 128;
    ushort_t* ctx16  = hv16 + (size_t)N * 128;
    ushort_t* Wih16  = ctx16 + (size_t)N * 128;
    ushort_t* Whh16  = Wih16 + 384 * 128;
    ushort_t* WpT16  = Whh16 + 384 * 128;

    float* outp = (float*)d_out;

    hipMemsetAsync(denom, 0, (size_t)2 * N * sizeof(float), stream);  // denom+count
    hipMemsetAsync(bn, 0, 256 * sizeof(float), stream);

    int nb_scan = (N + 255) / 256;   // 196 <= 256

    k_prep_w<<<(114688 + 255) / 256, 256, 0, stream>>>(W_ih, W_hh, W_proj,
                                                       Wih16, Whh16, WpT16);
    k_hv_fused<<<(N + 63) / 64, 256, 0, stream>>>(nf, WpT16, b_proj, W_edge,
                                                  nf16, hv16, s_d, s_s, N);
    k_edge<<<(E + 255) / 256, 256, 0, stream>>>(src, dst, s_d, s_s, b_edge,
                                                denom, count, E);
    k_scan_local<<<nb_scan, 256, 0, stream>>>(count, lex, bsum, N);
    k_scan_blocks<<<1, 256, 0, stream>>>(bsum, nb_scan);
    k_scan_apply<<<nb_scan, 256, 0, stream>>>(lex, bsum, row_start, cursor, N);
    k_fill<<<(E + 255) / 256, 256, 0, stream>>>(src, dst, s_d, s_s, b_edge,
                                                cursor, edge_u, edge_w, E);
    k_agg2<<<(N + 3) / 4, 256, 0, stream>>>(hv16, row_start, count, denom,
                                            edge_u, edge_w, ctx16, N);
    k_gru_mfma<<<(N + 127) / 128, 256, 0, stream>>>(ctx16, nf16, nf, Wih16, Whh16,
                                                    b_ih, b_hh, outp, N);
    k_bnstats<<<256, 128, 0, stream>>>(outp, bn, N);
    k_bnnorm<<<(N * D + 255) / 256, 256, 0, stream>>>(outp, bn, bn_g, bn_b, N);
}

// Round 4
// 253.286 us; speedup vs baseline: 2.8593x; 1.2764x over previous
//
#include <hip/hip_runtime.h>
#include <math.h>

constexpr int D = 128;

typedef __attribute__((ext_vector_type(8))) short short8;
typedef __attribute__((ext_vector_type(4))) float f32x4;
typedef unsigned short ushort_t;
typedef unsigned int uint_t;

__device__ inline ushort_t f2b(float x) {          // fp32 -> bf16 RNE
    uint_t u = __float_as_uint(x);
    uint_t r = u + 0x7fffu + ((u >> 16) & 1u);
    return (ushort_t)(r >> 16);
}
__device__ inline float b2f(ushort_t b) { return __uint_as_float(((uint_t)b) << 16); }

__device__ inline float sigm(float x) { return 1.f / (1.f + __expf(-x)); }
__device__ inline float tanh_(float x) {
    float t = __expf(-2.f * fabsf(x));
    float y = (1.f - t) / (1.f + t);
    return x >= 0.f ? y : -y;
}

// ---- convert weights to bf16 ---------------------------------------------
__global__ __launch_bounds__(256) void k_prep_w(
    const float* __restrict__ W_ih, const float* __restrict__ W_hh,
    const float* __restrict__ W_proj,
    ushort_t* __restrict__ Wih16, ushort_t* __restrict__ Whh16,
    ushort_t* __restrict__ WpT16)
{
    int idx = blockIdx.x * 256 + threadIdx.x;
    if (idx < 49152) {
        Wih16[idx] = f2b(W_ih[idx]);
    } else if (idx < 98304) {
        int i = idx - 49152;
        Whh16[i] = f2b(W_hh[i]);
    } else if (idx < 114688) {
        int t = idx - 98304;           // WpT[j][k] = W_proj[k][j]
        int j = t >> 7, k = t & 127;
        WpT16[t] = f2b(W_proj[k * 128 + j]);
    }
}

// ---- fused: nf->bf16, edge scores, hv = nf@WpT+b (MFMA, W in LDS) --------
__global__ __launch_bounds__(256, 2) void k_hv_fused(
    const float* __restrict__ nf, const ushort_t* __restrict__ WpT16,
    const float* __restrict__ b_proj, const float* __restrict__ W_edge,
    ushort_t* __restrict__ nf16, ushort_t* __restrict__ hv16,
    float* __restrict__ s_d, float* __restrict__ s_s, int N)
{
    __shared__ ushort_t plds[16384];           // 128 x 128 bf16 = 32 KB
    int w = threadIdx.x >> 6, lane = threadIdx.x & 63;
    int am = lane & 15, hi = lane >> 4, ak = hi * 8;

    // stage WpT into LDS once (swizzled: slot ^= row&15)
#pragma unroll
    for (int i = 0; i < 8; ++i) {
        int dl = (w * 8 + i) * 4 + hi;         // 0..127
        short8 v = *(const short8*)(WpT16 + (size_t)dl * 128 + am * 8);
        *(short8*)(plds + dl * 128 + ((am ^ (dl & 15)) * 8)) = v;
    }

    int r0 = blockIdx.x * 64 + w * 16;
    int arow = r0 + am;
    bool aok = arow < N;
    short8 A[4];
    float pd = 0.f, ps = 0.f;
#pragma unroll
    for (int kf = 0; kf < 4; ++kf) {
        int ko = kf * 32 + ak;
        float4 f0 = {0,0,0,0}, f1 = {0,0,0,0};
        if (aok) {
            f0 = *(const float4*)(nf + (size_t)arow * 128 + ko);
            f1 = *(const float4*)(nf + (size_t)arow * 128 + ko + 4);
        }
        pd += f0.x * W_edge[ko]     + f0.y * W_edge[ko + 1]
            + f0.z * W_edge[ko + 2] + f0.w * W_edge[ko + 3]
            + f1.x * W_edge[ko + 4] + f1.y * W_edge[ko + 5]
            + f1.z * W_edge[ko + 6] + f1.w * W_edge[ko + 7];
        ps += f0.x * W_edge[128+ko]     + f0.y * W_edge[128+ko+1]
            + f0.z * W_edge[128+ko+2]   + f0.w * W_edge[128+ko+3]
            + f1.x * W_edge[128+ko+4]   + f1.y * W_edge[128+ko+5]
            + f1.z * W_edge[128+ko+6]   + f1.w * W_edge[128+ko+7];
        short8 a;
        a[0] = (short)f2b(f0.x); a[1] = (short)f2b(f0.y);
        a[2] = (short)f2b(f0.z); a[3] = (short)f2b(f0.w);
        a[4] = (short)f2b(f1.x); a[5] = (short)f2b(f1.y);
        a[6] = (short)f2b(f1.z); a[7] = (short)f2b(f1.w);
        A[kf] = a;
        if (aok) *(short8*)(nf16 + (size_t)arow * 128 + ko) = a;
    }
    pd += __shfl_xor(pd, 16); pd += __shfl_xor(pd, 32);
    ps += __shfl_xor(ps, 16); ps += __shfl_xor(ps, 32);
    if (hi == 0 && aok) { s_d[arow] = pd; s_s[arow] = ps; }

    __syncthreads();                           // LDS weights ready

    int crow0 = r0 + hi * 4;
#pragma unroll 1
    for (int nc = 0; nc < 8; ++nc) {
        f32x4 acc = {0.f, 0.f, 0.f, 0.f};
        int col = nc * 16 + am;
#pragma unroll
        for (int kf = 0; kf < 4; ++kf) {
            short8 B = *(const short8*)(plds + col * 128 + (((kf * 4 + hi) ^ am) * 8));
            acc = __builtin_amdgcn_mfma_f32_16x16x32_bf16(A[kf], B, acc, 0, 0, 0);
        }
        float b = b_proj[col];
#pragma unroll
        for (int r = 0; r < 4; ++r) {
            int grow = crow0 + r;
            if (grow < N) hv16[(size_t)grow * 128 + col] = f2b(acc[r] + b);
        }
    }
}

// ---- pass 1 over edges: in-degree counts ---------------------------------
__global__ void k_edge(
    const int* __restrict__ dst, int* __restrict__ count, int E)
{
    int e = blockIdx.x * blockDim.x + threadIdx.x;
    if (e >= E) return;
    atomicAdd(&count[dst[e]], 1);
}

// ---- 3-phase scan for CSR row offsets ------------------------------------
__global__ __launch_bounds__(256) void k_scan_local(
    const int* __restrict__ count, int* __restrict__ lex,
    int* __restrict__ bsum, int N)
{
    __shared__ int sdata[256];
    int tid = threadIdx.x;
    int i = blockIdx.x * 256 + tid;
    int v = (i < N) ? count[i] : 0;
    int incl = v;
    sdata[tid] = incl; __syncthreads();
#pragma unroll
    for (int off = 1; off < 256; off <<= 1) {
        int add = (tid >= off) ? sdata[tid - off] : 0;
        __syncthreads();
        incl += add;
        sdata[tid] = incl;
        __syncthreads();
    }
    if (i < N) lex[i] = incl - v;
    if (tid == 255) bsum[blockIdx.x] = incl;
}

__global__ __launch_bounds__(256) void k_scan_blocks(int* __restrict__ bsum, int nb)
{
    __shared__ int sdata[256];
    int tid = threadIdx.x;
    int v = (tid < nb) ? bsum[tid] : 0;
    int incl = v;
    sdata[tid] = incl; __syncthreads();
#pragma unroll
    for (int off = 1; off < 256; off <<= 1) {
        int add = (tid >= off) ? sdata[tid - off] : 0;
        __syncthreads();
        incl += add;
        sdata[tid] = incl;
        __syncthreads();
    }
    if (tid < nb) bsum[tid] = incl - v;   // exclusive
}

__global__ __launch_bounds__(256) void k_scan_apply(
    const int* __restrict__ lex, const int* __restrict__ bsum,
    int* __restrict__ row_start, int* __restrict__ cursor, int N)
{
    int i = blockIdx.x * 256 + threadIdx.x;
    if (i < N) {
        int o = lex[i] + bsum[blockIdx.x];
        row_start[i] = o;
        cursor[i] = o;
    }
}

// ---- pass 2: fill CSR (edge_w = raw exp) ---------------------------------
__global__ void k_fill(
    const int* __restrict__ src, const int* __restrict__ dst,
    const float* __restrict__ s_d, const float* __restrict__ s_s,
    const float* __restrict__ b_edge,
    int* __restrict__ cursor, int* __restrict__ edge_u,
    float* __restrict__ edge_w, int E)
{
    int e = blockIdx.x * blockDim.x + threadIdx.x;
    if (e >= E) return;
    int s = src[e], t = dst[e];
    float l = s_d[t] + s_s[s] + b_edge[0];
    l = l > 0.f ? l : 0.01f * l;
    float ev = __expf(l);
    int pos = atomicAdd(&cursor[t], 1);
    edge_u[pos] = s;
    edge_w[pos] = ev;
}

// ---- aggregate: ctx = elu(num/den + one_sum), den inline -----------------
__global__ __launch_bounds__(256) void k_agg2(
    const ushort_t* __restrict__ hv16, const int* __restrict__ row_start,
    const int* __restrict__ count,
    const int* __restrict__ edge_u, const float* __restrict__ edge_w,
    ushort_t* __restrict__ ctx16, int N)
{
    int w = threadIdx.x >> 6, lane = threadIdx.x & 63;
    int v = blockIdx.x * 4 + w;
    if (v >= N) return;
    int beg = row_start[v], cnt = count[v];
    float num0 = 0.f, num1 = 0.f, one0 = 0.f, one1 = 0.f, den = 0.f;
    for (int chunk = 0; chunk < cnt; chunk += 64) {
        int m = min(64, cnt - chunk);
        int uu = 0; float ww = 0.f;
        if (lane < m) {
            uu = edge_u[beg + chunk + lane];
            ww = edge_w[beg + chunk + lane];
        }
        for (int i = 0; i < m; ++i) {
            int u = __shfl(uu, i);
            float ev = __shfl(ww, i);
            uint_t p = ((const uint_t*)(hv16 + (size_t)u * 128))[lane];
            float h0 = b2f((ushort_t)p);
            float h1 = b2f((ushort_t)(p >> 16));
            num0 = fmaf(h0, ev, num0);
            num1 = fmaf(h1, ev, num1);
            one0 += h0;
            one1 += h1;
            den += ev;
        }
    }
    float c0 = 0.f, c1 = 0.f;
    if (cnt > 0) {
        float inv = 1.f / den;
        c0 = num0 * inv + one0;
        c1 = num1 * inv + one1;
    }
    c0 = c0 > 0.f ? c0 : expm1f(c0);
    c1 = c1 > 0.f ? c1 : expm1f(c1);
    uint_t packed = (uint_t)f2b(c0) | ((uint_t)f2b(c1) << 16);
    ((uint_t*)ctx16)[(size_t)v * 64 + lane] = packed;
}

// ---- fused GRU: 32 rows/wave, weights double-buffered in LDS -------------
__global__ __launch_bounds__(256, 2) void k_gru_mfma(
    const ushort_t* __restrict__ ctx16, const ushort_t* __restrict__ nf16,
    const ushort_t* __restrict__ Wih16, const ushort_t* __restrict__ Whh16,
    const float* __restrict__ b_ih, const float* __restrict__ b_hh,
    float* __restrict__ out, int N)
{
    __shared__ ushort_t wlds[2 * 12288];   // 2 bufs x 6 mats x 16 cols x 128 k = 48 KB
    int w = threadIdx.x >> 6, lane = threadIdx.x & 63;
    int am = lane & 15, hi = lane >> 4, ak = hi * 8;
    int r0 = blockIdx.x * 128 + w * 32;

    short8 st[6];
    auto stage_load = [&](int cb) {
#pragma unroll
        for (int i = 0; i < 6; ++i) {
            int ch = w * 6 + i, m = ch >> 2, g = ch & 3;
            int dloc = g * 4 + hi;
            int wrow = (m >> 1) * 128 + cb * 16 + dloc;
            const ushort_t* sb = (m & 1) ? Whh16 : Wih16;
            st[i] = *(const short8*)(sb + (size_t)wrow * 128 + am * 8);
        }
    };
    auto stage_write = [&](int buf) {
#pragma unroll
        for (int i = 0; i < 6; ++i) {
            int ch = w * 6 + i, m = ch >> 2, g = ch & 3;
            int dloc = g * 4 + hi;
            *(short8*)(wlds + buf * 12288 + m * 2048 + dloc * 128 + ((am ^ dloc) * 8)) = st[i];
        }
    };

    stage_load(0);
    stage_write(0);

    // A fragments: 32 rows per wave from ctx16 / nf16
    short8 Ac[2][4], An[2][4];
#pragma unroll
    for (int rf = 0; rf < 2; ++rf) {
        int arow = r0 + rf * 16 + am;
        bool aok = arow < N;
        short8 z = {0,0,0,0,0,0,0,0};
#pragma unroll
        for (int kf = 0; kf < 4; ++kf) {
            size_t off = (size_t)arow * 128 + kf * 32 + ak;
            Ac[rf][kf] = aok ? *(const short8*)(ctx16 + off) : z;
            An[rf][kf] = aok ? *(const short8*)(nf16 + off) : z;
        }
    }

#pragma unroll 1
    for (int c = 0; c < 8; ++c) {
        __syncthreads();                       // buf[c&1] fully written
        int buf = c & 1;
        if (c < 7) stage_load(c + 1);

        int d = c * 16 + am;
        f32x4 racc[2], zacc[2], iacc[2], hacc[2];
#pragma unroll
        for (int rf = 0; rf < 2; ++rf) {
            racc[rf] = (f32x4){0.f,0.f,0.f,0.f};
            zacc[rf] = (f32x4){0.f,0.f,0.f,0.f};
            iacc[rf] = (f32x4){0.f,0.f,0.f,0.f};
            hacc[rf] = (f32x4){0.f,0.f,0.f,0.f};
        }
#pragma unroll
        for (int kf = 0; kf < 4; ++kf) {
            const ushort_t* bp = wlds + buf * 12288 + am * 128
                               + (((kf * 4 + hi) ^ am) * 8);
            short8 Br = *(const short8*)(bp + 0 * 2048);
            short8 Cr = *(const short8*)(bp + 1 * 2048);
            short8 Bz = *(const short8*)(bp + 2 * 2048);
            short8 Cz = *(const short8*)(bp + 3 * 2048);
            short8 Bi = *(const short8*)(bp + 4 * 2048);
            short8 Ch = *(const short8*)(bp + 5 * 2048);
#pragma unroll
            for (int rf = 0; rf < 2; ++rf) {
                racc[rf] = __builtin_amdgcn_mfma_f32_16x16x32_bf16(Ac[rf][kf], Br, racc[rf], 0, 0, 0);
                racc[rf] = __builtin_amdgcn_mfma_f32_16x16x32_bf16(An[rf][kf], Cr, racc[rf], 0, 0, 0);
                zacc[rf] = __builtin_amdgcn_mfma_f32_16x16x32_bf16(Ac[rf][kf], Bz, zacc[rf], 0, 0, 0);
                zacc[rf] = __builtin_amdgcn_mfma_f32_16x16x32_bf16(An[rf][kf], Cz, zacc[rf], 0, 0, 0);
                iacc[rf] = __builtin_amdgcn_mfma_f32_16x16x32_bf16(Ac[rf][kf], Bi, iacc[rf], 0, 0, 0);
                hacc[rf] = __builtin_amdgcn_mfma_f32_16x16x32_bf16(An[rf][kf], Ch, hacc[rf], 0, 0, 0);
            }
        }
        float br = b_ih[d] + b_hh[d];
        float bz = b_ih[128 + d] + b_hh[128 + d];
        float bi = b_ih[256 + d];
        float bh = b_hh[256 + d];
#pragma unroll
        for (int rf = 0; rf < 2; ++rf) {
            int crow0 = r0 + rf * 16 + hi * 4;
#pragma unroll
            for (int r = 0; r < 4; ++r) {
                int grow = crow0 + r;
                if (grow >= N) continue;
                float rv = sigm(racc[rf][r] + br);
                float zv = sigm(zacc[rf][r] + bz);
                float nv = tanh_(iacc[rf][r] + bi + rv * (hacc[rf][r] + bh));
                float hp = b2f(nf16[(size_t)grow * 128 + d]);
                float h = (1.f - zv) * nv + zv * hp;
                out[(size_t)grow * 128 + d] = fmaxf(h, 0.f);
            }
        }
        __syncthreads();                       // everyone done reading buf
        if (c < 7) stage_write(buf ^ 1);
    }
}

// ---- BatchNorm stats + normalize -----------------------------------------
__global__ __launch_bounds__(128) void k_bnstats(
    const float* __restrict__ out, float* __restrict__ bn, int N)
{
    int d = threadIdx.x;
    int nb = gridDim.x;
    int rows_per = (N + nb - 1) / nb;
    int r0 = blockIdx.x * rows_per;
    int r1 = min(N, r0 + rows_per);
    float s = 0.f, s2 = 0.f;
    for (int r = r0; r < r1; ++r) {
        float x = out[(size_t)r * 128 + d];
        s += x;
        s2 = fmaf(x, x, s2);
    }
    atomicAdd(&bn[d], s);
    atomicAdd(&bn[128 + d], s2);
}

__global__ __launch_bounds__(256) void k_bnnorm(
    float* __restrict__ out, const float* __restrict__ bn,
    const float* __restrict__ gamma, const float* __restrict__ beta, int N)
{
    int idx = blockIdx.x * 256 + threadIdx.x;
    int total = N * 128;
    if (idx >= total) return;
    int d = idx & 127;
    float invN = 1.f / (float)N;
    float mean = bn[d] * invN;
    float var = bn[128 + d] * invN - mean * mean;
    float inv_std = rsqrtf(var + 1e-5f);
    float x = out[idx];
    out[idx] = (x - mean) * inv_std * gamma[d] + beta[d];
}

// ---- host launcher -------------------------------------------------------
extern "C" void kernel_launch(void* const* d_in, const int* in_sizes, int n_in,
                              void* d_out, int out_size, void* d_ws, size_t ws_size,
                              hipStream_t stream)
{
    const float* nf     = (const float*)d_in[0];
    const int*   src    = (const int*)  d_in[1];
    const int*   dst    = (const int*)  d_in[2];
    const float* W_edge = (const float*)d_in[3];
    const float* b_edge = (const float*)d_in[4];
    const float* W_proj = (const float*)d_in[5];
    const float* b_proj = (const float*)d_in[6];
    const float* W_ih   = (const float*)d_in[7];
    const float* W_hh   = (const float*)d_in[8];
    const float* b_ih   = (const float*)d_in[9];
    const float* b_hh   = (const float*)d_in[10];
    const float* bn_g   = (const float*)d_in[11];
    const float* bn_b   = (const float*)d_in[12];

    const int N = in_sizes[0] / D;   // 50000
    const int E = in_sizes[1];       // 600000

    float* ws = (float*)d_ws;
    float* s_d       = ws;
    float* s_s       = ws + (size_t)N;
    int*   count     = (int*)(ws + (size_t)2 * N);
    int*   cursor    = (int*)(ws + (size_t)3 * N);
    int*   row_start = (int*)(ws + (size_t)4 * N);
    int*   lex       = (int*)(ws + (size_t)5 * N);
    int*   edge_u    = (int*)(ws + (size_t)6 * N);
    float* edge_w    = ws + (size_t)6 * N + (size_t)E;
    float* bn        = ws + (size_t)6 * N + (size_t)2 * E;
    int*   bsum      = (int*)(bn + 256);
    ushort_t* nf16   = (ushort_t*)(bn + 512);
    ushort_t* hv16   = nf16 + (size_t)N * 128;
    ushort_t* ctx16  = hv16 + (size_t)N * 128;
    ushort_t* Wih16  = ctx16 + (size_t)N * 128;
    ushort_t* Whh16  = Wih16 + 384 * 128;
    ushort_t* WpT16  = Whh16 + 384 * 128;

    float* outp = (float*)d_out;

    hipMemsetAsync(count, 0, (size_t)N * sizeof(int), stream);
    hipMemsetAsync(bn, 0, 256 * sizeof(float), stream);

    int nb_scan = (N + 255) / 256;   // 196 <= 256

    k_prep_w<<<(114688 + 255) / 256, 256, 0, stream>>>(W_ih, W_hh, W_proj,
                                                       Wih16, Whh16, WpT16);
    k_hv_fused<<<(N + 63) / 64, 256, 0, stream>>>(nf, WpT16, b_proj, W_edge,
                                                  nf16, hv16, s_d, s_s, N);
    k_edge<<<(E + 255) / 256, 256, 0, stream>>>(dst, count, E);
    k_scan_local<<<nb_scan, 256, 0, stream>>>(count, lex, bsum, N);
    k_scan_blocks<<<1, 256, 0, stream>>>(bsum, nb_scan);
    k_scan_apply<<<nb_scan, 256, 0, stream>>>(lex, bsum, row_start, cursor, N);
    k_fill<<<(E + 255) / 256, 256, 0, stream>>>(src, dst, s_d, s_s, b_edge,
                                                cursor, edge_u, edge_w, E);
    k_agg2<<<(N + 3) / 4, 256, 0, stream>>>(hv16, row_start, count,
                                            edge_u, edge_w, ctx16, N);
    k_gru_mfma<<<(N + 127) / 128, 256, 0, stream>>>(ctx16, nf16, Wih16, Whh16,
                                                    b_ih, b_hh, outp, N);
    k_bnstats<<<256, 128, 0, stream>>>(outp, bn, N);
    k_bnnorm<<<(N * D + 255) / 256, 256, 0, stream>>>(outp, bn, bn_g, bn_b, N);
}

// Round 5
// 221.967 us; speedup vs baseline: 3.2628x; 1.1411x over previous
//
#include <hip/hip_runtime.h>
#include <math.h>

constexpr int D = 128;

typedef __attribute__((ext_vector_type(8))) short short8;
typedef __attribute__((ext_vector_type(4))) float f32x4;
typedef unsigned short ushort_t;
typedef unsigned int uint_t;

__device__ inline ushort_t f2b(float x) {          // fp32 -> bf16 RNE
    uint_t u = __float_as_uint(x);
    uint_t r = u + 0x7fffu + ((u >> 16) & 1u);
    return (ushort_t)(r >> 16);
}
__device__ inline float b2f(ushort_t b) { return __uint_as_float(((uint_t)b) << 16); }

__device__ inline float sigm(float x) { return 1.f / (1.f + __expf(-x)); }
__device__ inline float tanh_(float x) {
    float t = __expf(-2.f * fabsf(x));
    float y = (1.f - t) / (1.f + t);
    return x >= 0.f ? y : -y;
}

// ---- convert weights to bf16 ---------------------------------------------
__global__ __launch_bounds__(256) void k_prep_w(
    const float* __restrict__ W_ih, const float* __restrict__ W_hh,
    const float* __restrict__ W_proj,
    ushort_t* __restrict__ Wih16, ushort_t* __restrict__ Whh16,
    ushort_t* __restrict__ WpT16)
{
    int idx = blockIdx.x * 256 + threadIdx.x;
    if (idx < 49152) {
        Wih16[idx] = f2b(W_ih[idx]);
    } else if (idx < 98304) {
        int i = idx - 49152;
        Whh16[i] = f2b(W_hh[i]);
    } else if (idx < 114688) {
        int t = idx - 98304;           // WpT[j][k] = W_proj[k][j]
        int j = t >> 7, k = t & 127;
        WpT16[t] = f2b(W_proj[k * 128 + j]);
    }
}

// ---- fused: nf->bf16, edge scores, hv = nf@WpT+b (MFMA, W in LDS) --------
__global__ __launch_bounds__(256, 2) void k_hv_fused(
    const float* __restrict__ nf, const ushort_t* __restrict__ WpT16,
    const float* __restrict__ b_proj, const float* __restrict__ W_edge,
    ushort_t* __restrict__ nf16, ushort_t* __restrict__ hv16,
    float* __restrict__ s_d, float* __restrict__ s_s, int N)
{
    __shared__ ushort_t plds[16384];           // 128 x 128 bf16 = 32 KB
    int w = threadIdx.x >> 6, lane = threadIdx.x & 63;
    int am = lane & 15, hi = lane >> 4, ak = hi * 8;

    // stage WpT into LDS once (swizzled: slot ^= row&15)
#pragma unroll
    for (int i = 0; i < 8; ++i) {
        int dl = (w * 8 + i) * 4 + hi;         // 0..127
        short8 v = *(const short8*)(WpT16 + (size_t)dl * 128 + am * 8);
        *(short8*)(plds + dl * 128 + ((am ^ (dl & 15)) * 8)) = v;
    }

    int r0 = blockIdx.x * 64 + w * 16;
    int arow = r0 + am;
    bool aok = arow < N;
    short8 A[4];
    float pd = 0.f, ps = 0.f;
#pragma unroll
    for (int kf = 0; kf < 4; ++kf) {
        int ko = kf * 32 + ak;
        float4 f0 = {0,0,0,0}, f1 = {0,0,0,0};
        if (aok) {
            f0 = *(const float4*)(nf + (size_t)arow * 128 + ko);
            f1 = *(const float4*)(nf + (size_t)arow * 128 + ko + 4);
        }
        pd += f0.x * W_edge[ko]     + f0.y * W_edge[ko + 1]
            + f0.z * W_edge[ko + 2] + f0.w * W_edge[ko + 3]
            + f1.x * W_edge[ko + 4] + f1.y * W_edge[ko + 5]
            + f1.z * W_edge[ko + 6] + f1.w * W_edge[ko + 7];
        ps += f0.x * W_edge[128+ko]     + f0.y * W_edge[128+ko+1]
            + f0.z * W_edge[128+ko+2]   + f0.w * W_edge[128+ko+3]
            + f1.x * W_edge[128+ko+4]   + f1.y * W_edge[128+ko+5]
            + f1.z * W_edge[128+ko+6]   + f1.w * W_edge[128+ko+7];
        short8 a;
        a[0] = (short)f2b(f0.x); a[1] = (short)f2b(f0.y);
        a[2] = (short)f2b(f0.z); a[3] = (short)f2b(f0.w);
        a[4] = (short)f2b(f1.x); a[5] = (short)f2b(f1.y);
        a[6] = (short)f2b(f1.z); a[7] = (short)f2b(f1.w);
        A[kf] = a;
        if (aok) *(short8*)(nf16 + (size_t)arow * 128 + ko) = a;
    }
    pd += __shfl_xor(pd, 16); pd += __shfl_xor(pd, 32);
    ps += __shfl_xor(ps, 16); ps += __shfl_xor(ps, 32);
    if (hi == 0 && aok) { s_d[arow] = pd; s_s[arow] = ps; }

    __syncthreads();                           // LDS weights ready

    int crow0 = r0 + hi * 4;
#pragma unroll 1
    for (int nc = 0; nc < 8; ++nc) {
        f32x4 acc = {0.f, 0.f, 0.f, 0.f};
        int col = nc * 16 + am;
#pragma unroll
        for (int kf = 0; kf < 4; ++kf) {
            short8 B = *(const short8*)(plds + col * 128 + (((kf * 4 + hi) ^ am) * 8));
            acc = __builtin_amdgcn_mfma_f32_16x16x32_bf16(A[kf], B, acc, 0, 0, 0);
        }
        float b = b_proj[col];
#pragma unroll
        for (int r = 0; r < 4; ++r) {
            int grow = crow0 + r;
            if (grow < N) hv16[(size_t)grow * 128 + col] = f2b(acc[r] + b);
        }
    }
}

// ---- pass 1 over edges: in-degree counts ---------------------------------
__global__ void k_edge(
    const int* __restrict__ dst, int* __restrict__ count, int E)
{
    int e = blockIdx.x * blockDim.x + threadIdx.x;
    if (e >= E) return;
    atomicAdd(&count[dst[e]], 1);
}

// ---- 3-phase scan for CSR row offsets ------------------------------------
__global__ __launch_bounds__(256) void k_scan_local(
    const int* __restrict__ count, int* __restrict__ lex,
    int* __restrict__ bsum, int N)
{
    __shared__ int sdata[256];
    int tid = threadIdx.x;
    int i = blockIdx.x * 256 + tid;
    int v = (i < N) ? count[i] : 0;
    int incl = v;
    sdata[tid] = incl; __syncthreads();
#pragma unroll
    for (int off = 1; off < 256; off <<= 1) {
        int add = (tid >= off) ? sdata[tid - off] : 0;
        __syncthreads();
        incl += add;
        sdata[tid] = incl;
        __syncthreads();
    }
    if (i < N) lex[i] = incl - v;
    if (tid == 255) bsum[blockIdx.x] = incl;
}

__global__ __launch_bounds__(256) void k_scan_blocks(int* __restrict__ bsum, int nb)
{
    __shared__ int sdata[256];
    int tid = threadIdx.x;
    int v = (tid < nb) ? bsum[tid] : 0;
    int incl = v;
    sdata[tid] = incl; __syncthreads();
#pragma unroll
    for (int off = 1; off < 256; off <<= 1) {
        int add = (tid >= off) ? sdata[tid - off] : 0;
        __syncthreads();
        incl += add;
        sdata[tid] = incl;
        __syncthreads();
    }
    if (tid < nb) bsum[tid] = incl - v;   // exclusive
}

__global__ __launch_bounds__(256) void k_scan_apply(
    const int* __restrict__ lex, const int* __restrict__ bsum,
    int* __restrict__ row_start, int* __restrict__ cursor, int N)
{
    int i = blockIdx.x * 256 + threadIdx.x;
    if (i < N) {
        int o = lex[i] + bsum[blockIdx.x];
        row_start[i] = o;
        cursor[i] = o;
    }
}

// ---- pass 2: fill CSR with src indices only (atomicExch -> L2-alloc) -----
__global__ void k_fill(
    const int* __restrict__ src, const int* __restrict__ dst,
    int* __restrict__ cursor, uint_t* __restrict__ perm_u, int E)
{
    int e = blockIdx.x * blockDim.x + threadIdx.x;
    if (e >= E) return;
    int s = src[e], t = dst[e];
    int pos = atomicAdd(&cursor[t], 1);
    atomicExch(&perm_u[pos], (uint_t)s);
}

// ---- aggregate: recompute softmax weights, ctx = elu(num/den + one) ------
__global__ __launch_bounds__(256) void k_agg2(
    const ushort_t* __restrict__ hv16, const int* __restrict__ row_start,
    const int* __restrict__ count, const float* __restrict__ s_d,
    const float* __restrict__ s_s, const float* __restrict__ b_edge,
    const uint_t* __restrict__ perm_u, ushort_t* __restrict__ ctx16, int N)
{
    int w = threadIdx.x >> 6, lane = threadIdx.x & 63;
    int v = blockIdx.x * 4 + w;
    if (v >= N) return;
    int beg = row_start[v], cnt = count[v];
    float sdv = s_d[v] + b_edge[0];
    float num0 = 0.f, num1 = 0.f, one0 = 0.f, one1 = 0.f, den = 0.f;
    for (int chunk = 0; chunk < cnt; chunk += 64) {
        int m = min(64, cnt - chunk);
        int uu = 0; float ev = 0.f;
        if (lane < m) {
            uu = (int)perm_u[beg + chunk + lane];
            float l = sdv + s_s[uu];
            l = l > 0.f ? l : 0.01f * l;
            ev = __expf(l);
        }
        for (int i = 0; i < m; ++i) {
            int u = __shfl(uu, i);
            float e = __shfl(ev, i);
            uint_t p = ((const uint_t*)(hv16 + (size_t)u * 128))[lane];
            float h0 = b2f((ushort_t)p);
            float h1 = b2f((ushort_t)(p >> 16));
            num0 = fmaf(h0, e, num0);
            num1 = fmaf(h1, e, num1);
            one0 += h0;
            one1 += h1;
            den += e;
        }
    }
    float c0 = 0.f, c1 = 0.f;
    if (cnt > 0) {
        float inv = 1.f / den;
        c0 = num0 * inv + one0;
        c1 = num1 * inv + one1;
    }
    c0 = c0 > 0.f ? c0 : expm1f(c0);
    c1 = c1 > 0.f ? c1 : expm1f(c1);
    uint_t packed = (uint_t)f2b(c0) | ((uint_t)f2b(c1) << 16);
    ((uint_t*)ctx16)[(size_t)v * 64 + lane] = packed;
}

// ---- fused GRU + relu + BN-stats (weights double-buffered in LDS) --------
__global__ __launch_bounds__(256, 2) void k_gru_mfma(
    const ushort_t* __restrict__ ctx16, const ushort_t* __restrict__ nf16,
    const ushort_t* __restrict__ Wih16, const ushort_t* __restrict__ Whh16,
    const float* __restrict__ b_ih, const float* __restrict__ b_hh,
    float* __restrict__ out, float* __restrict__ bn, int N)
{
    __shared__ ushort_t wlds[2 * 12288];   // 48 KB
    __shared__ float bnsum[2][4][128];     // 4 KB  [s|s2][wave][col]
    int w = threadIdx.x >> 6, lane = threadIdx.x & 63;
    int am = lane & 15, hi = lane >> 4, ak = hi * 8;
    int r0 = blockIdx.x * 128 + w * 32;

    for (int i = threadIdx.x; i < 1024; i += 256)
        ((float*)bnsum)[i] = 0.f;

    short8 st[6];
    auto stage_load = [&](int cb) {
#pragma unroll
        for (int i = 0; i < 6; ++i) {
            int ch = w * 6 + i, m = ch >> 2, g = ch & 3;
            int dloc = g * 4 + hi;
            int wrow = (m >> 1) * 128 + cb * 16 + dloc;
            const ushort_t* sb = (m & 1) ? Whh16 : Wih16;
            st[i] = *(const short8*)(sb + (size_t)wrow * 128 + am * 8);
        }
    };
    auto stage_write = [&](int buf) {
#pragma unroll
        for (int i = 0; i < 6; ++i) {
            int ch = w * 6 + i, m = ch >> 2, g = ch & 3;
            int dloc = g * 4 + hi;
            *(short8*)(wlds + buf * 12288 + m * 2048 + dloc * 128 + ((am ^ dloc) * 8)) = st[i];
        }
    };

    stage_load(0);
    stage_write(0);

    short8 Ac[2][4], An[2][4];
#pragma unroll
    for (int rf = 0; rf < 2; ++rf) {
        int arow = r0 + rf * 16 + am;
        bool aok = arow < N;
        short8 z = {0,0,0,0,0,0,0,0};
#pragma unroll
        for (int kf = 0; kf < 4; ++kf) {
            size_t off = (size_t)arow * 128 + kf * 32 + ak;
            Ac[rf][kf] = aok ? *(const short8*)(ctx16 + off) : z;
            An[rf][kf] = aok ? *(const short8*)(nf16 + off) : z;
        }
    }

#pragma unroll 1
    for (int c = 0; c < 8; ++c) {
        __syncthreads();                       // buf[c&1] fully written
        int buf = c & 1;
        if (c < 7) stage_load(c + 1);

        int d = c * 16 + am;
        f32x4 racc[2], zacc[2], iacc[2], hacc[2];
#pragma unroll
        for (int rf = 0; rf < 2; ++rf) {
            racc[rf] = (f32x4){0.f,0.f,0.f,0.f};
            zacc[rf] = (f32x4){0.f,0.f,0.f,0.f};
            iacc[rf] = (f32x4){0.f,0.f,0.f,0.f};
            hacc[rf] = (f32x4){0.f,0.f,0.f,0.f};
        }
#pragma unroll
        for (int kf = 0; kf < 4; ++kf) {
            const ushort_t* bp = wlds + buf * 12288 + am * 128
                               + (((kf * 4 + hi) ^ am) * 8);
            short8 Br = *(const short8*)(bp + 0 * 2048);
            short8 Cr = *(const short8*)(bp + 1 * 2048);
            short8 Bz = *(const short8*)(bp + 2 * 2048);
            short8 Cz = *(const short8*)(bp + 3 * 2048);
            short8 Bi = *(const short8*)(bp + 4 * 2048);
            short8 Ch = *(const short8*)(bp + 5 * 2048);
#pragma unroll
            for (int rf = 0; rf < 2; ++rf) {
                racc[rf] = __builtin_amdgcn_mfma_f32_16x16x32_bf16(Ac[rf][kf], Br, racc[rf], 0, 0, 0);
                racc[rf] = __builtin_amdgcn_mfma_f32_16x16x32_bf16(An[rf][kf], Cr, racc[rf], 0, 0, 0);
                zacc[rf] = __builtin_amdgcn_mfma_f32_16x16x32_bf16(Ac[rf][kf], Bz, zacc[rf], 0, 0, 0);
                zacc[rf] = __builtin_amdgcn_mfma_f32_16x16x32_bf16(An[rf][kf], Cz, zacc[rf], 0, 0, 0);
                iacc[rf] = __builtin_amdgcn_mfma_f32_16x16x32_bf16(Ac[rf][kf], Bi, iacc[rf], 0, 0, 0);
                hacc[rf] = __builtin_amdgcn_mfma_f32_16x16x32_bf16(An[rf][kf], Ch, hacc[rf], 0, 0, 0);
            }
        }
        float br = b_ih[d] + b_hh[d];
        float bz = b_ih[128 + d] + b_hh[128 + d];
        float bi = b_ih[256 + d];
        float bh = b_hh[256 + d];
        float cs = 0.f, cs2 = 0.f;
#pragma unroll
        for (int rf = 0; rf < 2; ++rf) {
            int crow0 = r0 + rf * 16 + hi * 4;
#pragma unroll
            for (int r = 0; r < 4; ++r) {
                int grow = crow0 + r;
                if (grow >= N) continue;
                float rv = sigm(racc[rf][r] + br);
                float zv = sigm(zacc[rf][r] + bz);
                float nv = tanh_(iacc[rf][r] + bi + rv * (hacc[rf][r] + bh));
                float hp = b2f(nf16[(size_t)grow * 128 + d]);
                float h = (1.f - zv) * nv + zv * hp;
                h = fmaxf(h, 0.f);
                out[(size_t)grow * 128 + d] = h;
                cs += h;
                cs2 = fmaf(h, h, cs2);
            }
        }
        cs  += __shfl_xor(cs, 16);  cs  += __shfl_xor(cs, 32);
        cs2 += __shfl_xor(cs2, 16); cs2 += __shfl_xor(cs2, 32);
        if (hi == 0) {
            bnsum[0][w][d] += cs;
            bnsum[1][w][d] += cs2;
        }
        __syncthreads();                       // everyone done reading buf
        if (c < 7) stage_write(buf ^ 1);
    }
    __syncthreads();
    int t = threadIdx.x;
    if (t < 128) {
        float s = bnsum[0][0][t] + bnsum[0][1][t] + bnsum[0][2][t] + bnsum[0][3][t];
        atomicAdd(&bn[t], s);
    } else {
        int d2 = t - 128;
        float s2 = bnsum[1][0][d2] + bnsum[1][1][d2] + bnsum[1][2][d2] + bnsum[1][3][d2];
        atomicAdd(&bn[128 + d2], s2);
    }
}

// ---- BatchNorm normalize -------------------------------------------------
__global__ __launch_bounds__(256) void k_bnnorm(
    float* __restrict__ out, const float* __restrict__ bn,
    const float* __restrict__ gamma, const float* __restrict__ beta, int N)
{
    int idx = blockIdx.x * 256 + threadIdx.x;
    int total = N * 128;
    if (idx >= total) return;
    int d = idx & 127;
    float invN = 1.f / (float)N;
    float mean = bn[d] * invN;
    float var = bn[128 + d] * invN - mean * mean;
    float inv_std = rsqrtf(var + 1e-5f);
    float x = out[idx];
    out[idx] = (x - mean) * inv_std * gamma[d] + beta[d];
}

// ---- host launcher -------------------------------------------------------
extern "C" void kernel_launch(void* const* d_in, const int* in_sizes, int n_in,
                              void* d_out, int out_size, void* d_ws, size_t ws_size,
                              hipStream_t stream)
{
    const float* nf     = (const float*)d_in[0];
    const int*   src    = (const int*)  d_in[1];
    const int*   dst    = (const int*)  d_in[2];
    const float* W_edge = (const float*)d_in[3];
    const float* b_edge = (const float*)d_in[4];
    const float* W_proj = (const float*)d_in[5];
    const float* b_proj = (const float*)d_in[6];
    const float* W_ih   = (const float*)d_in[7];
    const float* W_hh   = (const float*)d_in[8];
    const float* b_ih   = (const float*)d_in[9];
    const float* b_hh   = (const float*)d_in[10];
    const float* bn_g   = (const float*)d_in[11];
    const float* bn_b   = (const float*)d_in[12];

    const int N = in_sizes[0] / D;   // 50000
    const int E = in_sizes[1];       // 600000

    float* ws = (float*)d_ws;
    float* s_d       = ws;
    float* s_s       = ws + (size_t)N;
    int*   count     = (int*)(ws + (size_t)2 * N);
    int*   cursor    = (int*)(ws + (size_t)3 * N);
    int*   row_start = (int*)(ws + (size_t)4 * N);
    int*   lex       = (int*)(ws + (size_t)5 * N);
    uint_t* perm_u   = (uint_t*)(ws + (size_t)6 * N);
    float* bn        = ws + (size_t)6 * N + (size_t)E;
    int*   bsum      = (int*)(bn + 256);
    ushort_t* nf16   = (ushort_t*)(bn + 512);
    ushort_t* hv16   = nf16 + (size_t)N * 128;
    ushort_t* ctx16  = hv16 + (size_t)N * 128;
    ushort_t* Wih16  = ctx16 + (size_t)N * 128;
    ushort_t* Whh16  = Wih16 + 384 * 128;
    ushort_t* WpT16  = Whh16 + 384 * 128;

    float* outp = (float*)d_out;

    hipMemsetAsync(count, 0, (size_t)N * sizeof(int), stream);
    hipMemsetAsync(bn, 0, 256 * sizeof(float), stream);

    int nb_scan = (N + 255) / 256;   // 196 <= 256

    k_prep_w<<<(114688 + 255) / 256, 256, 0, stream>>>(W_ih, W_hh, W_proj,
                                                       Wih16, Whh16, WpT16);
    k_hv_fused<<<(N + 63) / 64, 256, 0, stream>>>(nf, WpT16, b_proj, W_edge,
                                                  nf16, hv16, s_d, s_s, N);
    k_edge<<<(E + 255) / 256, 256, 0, stream>>>(dst, count, E);
    k_scan_local<<<nb_scan, 256, 0, stream>>>(count, lex, bsum, N);
    k_scan_blocks<<<1, 256, 0, stream>>>(bsum, nb_scan);
    k_scan_apply<<<nb_scan, 256, 0, stream>>>(lex, bsum, row_start, cursor, N);
    k_fill<<<(E + 255) / 256, 256, 0, stream>>>(src, dst, cursor, perm_u, E);
    k_agg2<<<(N + 3) / 4, 256, 0, stream>>>(hv16, row_start, count, s_d, s_s,
                                            b_edge, perm_u, ctx16, N);
    k_gru_mfma<<<(N + 127) / 128, 256, 0, stream>>>(ctx16, nf16, Wih16, Whh16,
                                                    b_ih, b_hh, outp, bn, N);
    k_bnnorm<<<(N * D + 255) / 256, 256, 0, stream>>>(outp, bn, bn_g, bn_b, N);
}